// Round 1
// baseline (255.459 us; speedup 1.0000x reference)
//
#include <hip/hip_runtime.h>
#include <hip/hip_bf16.h>

// Causal attention, S=4096, d=1024, fp32 in/out, bf16 MFMA internally.
// Math note: reference's full-row softmax -> tril mask -> renormalize is
// EXACTLY causal softmax (full-row max & Z cancel in the ratio), so we only
// compute the lower triangle.
//
// Workspace layout (70 MB total):
//   [0,8M)    x_bf    [4096,1024] bf16
//   [8M,12M)  Wqk     [2048,1024] bf16  (Wq rows 0..1023, Wk rows 1024..2047)
//   [12M,14M) Wv_bf   [1024,1024] bf16
//   [14M,30M) QK      [4096,2048] bf16  (Q cols 0..1023, K cols 1024..2047)
//   [30M,38M) Vt      [1024,4096] bf16  (V transposed: computed as Wv @ x^T)
//   [38M,70M) S/P     [4096,4096] bf16  (scores, overwritten by probs in-place)

typedef __bf16 bf16_t;
typedef __bf16 bf16x4 __attribute__((ext_vector_type(4)));
typedef __bf16 bf16x8 __attribute__((ext_vector_type(8)));
typedef float f32x4 __attribute__((ext_vector_type(4)));

#define AS1 __attribute__((address_space(1)))
#define AS3 __attribute__((address_space(3)))

__device__ __forceinline__ void async_copy16(const void* g, void* l) {
    // 16B per lane, direct global->LDS (DMA), LDS dest = wave-uniform base + lane*16
    __builtin_amdgcn_global_load_lds((AS1 void*)(g), (AS3 void*)(l), 16, 0, 0);
}

// C[m,n] = alpha * sum_k A[m,k] * B[n,k]   (both operands K-contiguous, "NT")
// CMODE: 0 = full, 1 = causal block skip (bn>bm exit; for S=Q@K^T),
//        2 = per-row-block K limit (K_eff = (bm+1)*BM; for O=P@V)
template <int CMODE, bool OUTBF16>
__global__ __launch_bounds__(256) void gemm_nt(const bf16_t* __restrict__ A, int lda,
                                               const bf16_t* __restrict__ B, int ldb,
                                               void* __restrict__ Cp, int ldc,
                                               int K, float alpha) {
    constexpr int BM = 128, BN = 128, BK = 64;
    __shared__ __attribute__((aligned(16))) bf16_t As[BM * BK];
    __shared__ __attribute__((aligned(16))) bf16_t Bs[BN * BK];

    const int bn = blockIdx.x, bm = blockIdx.y;
    if (CMODE == 1 && bn > bm) return;

    const int tid  = threadIdx.x;
    const int lane = tid & 63, wave = tid >> 6;
    const int wm = wave >> 1, wn = wave & 1;   // 2x2 waves, each 64x64 out
    const int q = lane >> 4, l16 = lane & 15;

    int nk = K / BK;
    if (CMODE == 2) nk = min(nk, ((bm + 1) * BM) / BK);

    f32x4 acc[4][4] = {};

    // Staging: 1024 16B-chunks per 128x64 tile; 4 per thread per tile.
    // XOR swizzle: LDS chunk (row r, slot b) holds global k-block (b ^ (r&7))
    // -> ds_read_b128 of a fragment hits all 32 banks (2-way alias = free).
    const bf16_t* aSrc[4];
    const bf16_t* bSrc[4];
    int ldsOff[4];
#pragma unroll
    for (int it = 0; it < 4; ++it) {
        int c = it * 256 + tid;
        int r = c >> 3, b = c & 7;
        int sb = b ^ (r & 7);
        aSrc[it] = A + (size_t)(bm * BM + r) * lda + sb * 8;
        bSrc[it] = B + (size_t)(bn * BN + r) * ldb + sb * 8;
        ldsOff[it] = c * 8;
    }

    for (int kb = 0; kb < nk; ++kb) {
        const int k0 = kb * BK;
#pragma unroll
        for (int it = 0; it < 4; ++it) async_copy16(aSrc[it] + k0, &As[ldsOff[it]]);
#pragma unroll
        for (int it = 0; it < 4; ++it) async_copy16(bSrc[it] + k0, &Bs[ldsOff[it]]);
        __syncthreads();  // compiler emits vmcnt(0) drain before s_barrier

#pragma unroll
        for (int k2 = 0; k2 < 2; ++k2) {
            bf16x8 af[4], bfr[4];
#pragma unroll
            for (int mt = 0; mt < 4; ++mt) {
                int m = wm * 64 + mt * 16 + l16;
                int blk = (k2 * 4 + q) ^ (m & 7);
                af[mt] = *(const bf16x8*)&As[m * BK + blk * 8];
            }
#pragma unroll
            for (int nt = 0; nt < 4; ++nt) {
                int nn = wn * 64 + nt * 16 + l16;
                int blk = (k2 * 4 + q) ^ (nn & 7);
                bfr[nt] = *(const bf16x8*)&Bs[nn * BK + blk * 8];
            }
#pragma unroll
            for (int mt = 0; mt < 4; ++mt)
#pragma unroll
                for (int nt = 0; nt < 4; ++nt)
                    acc[mt][nt] = __builtin_amdgcn_mfma_f32_16x16x32_bf16(
                        af[mt], bfr[nt], acc[mt][nt], 0, 0, 0);
        }
        __syncthreads();  // all waves done reading before next stage overwrites
    }

    // Epilogue. C/D layout: col = lane&15, row = (lane>>4)*4 + reg
    const int row0 = bm * BM + wm * 64;
    const int col0 = bn * BN + wn * 64;
#pragma unroll
    for (int mt = 0; mt < 4; ++mt) {
#pragma unroll
        for (int nt = 0; nt < 4; ++nt) {
#pragma unroll
            for (int r = 0; r < 4; ++r) {
                int grow = row0 + mt * 16 + q * 4 + r;
                int gcol = col0 + nt * 16 + l16;
                float v = acc[mt][nt][r] * alpha;
                if (OUTBF16)
                    ((bf16_t*)Cp)[(size_t)grow * ldc + gcol] = (bf16_t)v;
                else
                    ((float*)Cp)[(size_t)grow * ldc + gcol] = v;
            }
        }
    }
}

// One block per row i: causal softmax over S[i, 0..i], in place (bf16),
// zero-fills up to the end of the diagonal 128-block so the PV GEMM can
// read whole 128-wide K-blocks.
__global__ __launch_bounds__(256) void softmax_causal(bf16_t* __restrict__ S, int n) {
    const int i = blockIdx.x;
    const int L = i + 1;
    const int Lpad = min(n, ((i >> 7) + 1) << 7);
    __shared__ float buf[4096];
    __shared__ float red[8];
    bf16_t* row = S + (size_t)i * n;

    for (int j = threadIdx.x; j < L; j += 256) buf[j] = (float)row[j];
    __syncthreads();

    float m = -3.4e38f;
    for (int j = threadIdx.x; j < L; j += 256) m = fmaxf(m, buf[j]);
#pragma unroll
    for (int off = 32; off; off >>= 1) m = fmaxf(m, __shfl_xor(m, off, 64));
    if ((threadIdx.x & 63) == 0) red[threadIdx.x >> 6] = m;
    __syncthreads();
    m = fmaxf(fmaxf(red[0], red[1]), fmaxf(red[2], red[3]));

    float s = 0.f;
    for (int j = threadIdx.x; j < L; j += 256) s += __expf(buf[j] - m);
#pragma unroll
    for (int off = 32; off; off >>= 1) s += __shfl_xor(s, off, 64);
    if ((threadIdx.x & 63) == 0) red[4 + (threadIdx.x >> 6)] = s;
    __syncthreads();
    s = (red[4] + red[5]) + (red[6] + red[7]);
    float inv = 1.f / s;

    for (int j = threadIdx.x; j < Lpad; j += 256) {
        float p = (j < L) ? __expf(buf[j] - m) * inv : 0.f;
        row[j] = (bf16_t)p;
    }
}

// fp32 -> bf16 casts: x -> x_bf, Wq|Wk -> Wqk (concat), Wv -> Wv_bf.
// 4 floats per thread, float4 in, packed bf16x4 out.
__global__ __launch_bounds__(256) void cast_to_bf16(const float* __restrict__ x,
                                                    const float* __restrict__ Wq,
                                                    const float* __restrict__ Wk,
                                                    const float* __restrict__ Wv,
                                                    bf16_t* __restrict__ xb,
                                                    bf16_t* __restrict__ wqk,
                                                    bf16_t* __restrict__ wv) {
    const int NX = (4096 * 1024) / 4;
    const int NW = (1024 * 1024) / 4;
    int idx = blockIdx.x * 256 + threadIdx.x;
    const float* src;
    bf16_t* dst;
    int off;
    if (idx < NX) {
        src = x; dst = xb; off = idx;
    } else if (idx < NX + NW) {
        src = Wq; dst = wqk; off = idx - NX;
    } else if (idx < NX + 2 * NW) {
        src = Wk; dst = wqk + (size_t)NW * 4; off = idx - NX - NW;
    } else {
        src = Wv; dst = wv; off = idx - NX - 2 * NW;
    }
    float4 f = ((const float4*)src)[off];
    bf16x4 o;
    o.x = (bf16_t)f.x; o.y = (bf16_t)f.y; o.z = (bf16_t)f.z; o.w = (bf16_t)f.w;
    *(bf16x4*)(dst + (size_t)off * 4) = o;
}

extern "C" void kernel_launch(void* const* d_in, const int* in_sizes, int n_in,
                              void* d_out, int out_size, void* d_ws, size_t ws_size,
                              hipStream_t stream) {
    (void)in_sizes; (void)n_in; (void)out_size; (void)ws_size;
    const float* x  = (const float*)d_in[0];
    const float* Wq = (const float*)d_in[1];
    const float* Wk = (const float*)d_in[2];
    const float* Wv = (const float*)d_in[3];
    float* out = (float*)d_out;

    char* ws = (char*)d_ws;
    bf16_t* xb  = (bf16_t*)(ws + (size_t)0);
    bf16_t* wqk = (bf16_t*)(ws + ((size_t)8 << 20));
    bf16_t* wvb = (bf16_t*)(ws + ((size_t)12 << 20));
    bf16_t* qk  = (bf16_t*)(ws + ((size_t)14 << 20));
    bf16_t* vt  = (bf16_t*)(ws + ((size_t)30 << 20));
    bf16_t* S   = (bf16_t*)(ws + ((size_t)38 << 20));

    // 1) casts (1835008 threads of 4 elts)
    cast_to_bf16<<<7168, 256, 0, stream>>>(x, Wq, Wk, Wv, xb, wqk, wvb);

    // 2) QK = x @ [Wq;Wk]^T  -> [4096, 2048] bf16
    gemm_nt<0, true><<<dim3(16, 32), 256, 0, stream>>>(xb, 1024, wqk, 1024, qk, 2048, 1024, 1.0f);

    // 3) Vt = Wv @ x^T -> [1024, 4096] bf16  (V transposed, K-contig for PV)
    gemm_nt<0, true><<<dim3(32, 8), 256, 0, stream>>>(wvb, 1024, xb, 1024, vt, 4096, 1024, 1.0f);

    // 4) S = (Q @ K^T) / 32, lower-triangular blocks only -> [4096,4096] bf16
    gemm_nt<1, true><<<dim3(32, 32), 256, 0, stream>>>(qk, 2048, qk + 1024, 2048, S, 4096, 1024,
                                                       0.03125f);

    // 5) causal softmax rows, in place
    softmax_causal<<<4096, 256, 0, stream>>>(S, 4096);

    // 6) out = P @ V  (B = Vt, K limited to (bm+1)*128 per row-block), fp32
    gemm_nt<2, false><<<dim3(8, 32), 256, 0, stream>>>(S, 4096, vt, 4096, out, 1024, 4096, 1.0f);
}

// Round 2
// 223.585 us; speedup vs baseline: 1.1426x; 1.1426x over previous
//
#include <hip/hip_runtime.h>
#include <hip/hip_bf16.h>

// Causal attention, S=4096, d=1024, fp32 in/out, bf16 MFMA internally.
// Reference's full-row softmax -> tril -> renormalize == causal softmax
// (row max & Z cancel), so only the lower triangle is computed.
//
// Round-2 structure (fix: all GEMMs were at 1-2 blocks/CU -> latency-bound,
// MfmaUtil 8%):
//  - QK-proj and Vt-proj fused into one 768-block dispatch (3 blocks/CU)
//  - S-GEMM at 128x64 tiles -> 1056 causal blocks (4.1/CU)
//  - PV as split-K (chunks of K=1024) -> 640 balanced blocks + f32 atomics
//
// Workspace layout (70 MB):
//   [0,8M)    x_bf  [4096,1024] bf16
//   [8M,12M)  Wqk   [2048,1024] bf16   (Wq rows 0..1023, Wk rows 1024..2047)
//   [12M,14M) Wv_bf [1024,1024] bf16
//   [14M,30M) QK    [4096,2048] bf16   (Q cols 0..1023, K cols 1024..2047)
//   [30M,38M) Vt    [1024,4096] bf16   (V^T, computed directly as Wv @ x^T)
//   [38M,70M) S/P   [4096,4096] bf16   (scores -> probs in place)

typedef __bf16 bf16_t;
typedef __bf16 bf16x4 __attribute__((ext_vector_type(4)));
typedef __bf16 bf16x8 __attribute__((ext_vector_type(8)));
typedef float f32x4 __attribute__((ext_vector_type(4)));

#define AS1 __attribute__((address_space(1)))
#define AS3 __attribute__((address_space(3)))

__device__ __forceinline__ void async_copy16(const void* g, void* l) {
    // 16B/lane direct global->LDS; LDS dest = wave-uniform base + lane*16
    __builtin_amdgcn_global_load_lds((AS1 void*)(g), (AS3 void*)(l), 16, 0, 0);
}

// One 128xBN output tile of C = alpha * A.B^T (both K-contiguous, "NT").
// BK=64, XOR-swizzled LDS (chunk b of row r holds k-block b^(r&7)) -> zero
// bank conflicts on both the staging writes and the ds_read_b128 fragments.
// kb in [kb0, kb1) allows split-K; ATOMIC epilogue accumulates into fp32 C.
template <int BN, bool OUTBF16, bool ATOMIC>
__device__ __forceinline__ void gemm_tile(const bf16_t* __restrict__ A, int lda,
                                          const bf16_t* __restrict__ B, int ldb,
                                          void* __restrict__ Cp, int ldc,
                                          int bm, int bn, int kb0, int kb1, float alpha,
                                          bf16_t* __restrict__ As, bf16_t* __restrict__ Bs) {
    constexpr int BM = 128, BK = 64;
    constexpr int NT = BN / 32;   // 16-col MFMA tiles per wave (wave = 64 x BN/2)
    constexpr int NCB = BN / 32;  // B staging chunks per thread

    const int tid = threadIdx.x;
    const int lane = tid & 63, wave = tid >> 6;
    const int wm = wave >> 1, wn = wave & 1;
    const int q = lane >> 4, l16 = lane & 15;

    f32x4 acc[4][NT] = {};

    const bf16_t* aSrc[4];
    int aOff[4];
#pragma unroll
    for (int it = 0; it < 4; ++it) {
        int c = it * 256 + tid;
        int r = c >> 3, b = c & 7;
        int sb = b ^ (r & 7);
        aSrc[it] = A + (size_t)(bm * BM + r) * lda + sb * 8;
        aOff[it] = c * 8;
    }
    const bf16_t* bSrc[NCB];
    int bOff[NCB];
#pragma unroll
    for (int it = 0; it < NCB; ++it) {
        int c = it * 256 + tid;
        int r = c >> 3, b = c & 7;
        int sb = b ^ (r & 7);
        bSrc[it] = B + (size_t)(bn * BN + r) * ldb + sb * 8;
        bOff[it] = c * 8;
    }

    for (int kb = kb0; kb < kb1; ++kb) {
        const int k0 = kb * BK;
#pragma unroll
        for (int it = 0; it < 4; ++it) async_copy16(aSrc[it] + k0, &As[aOff[it]]);
#pragma unroll
        for (int it = 0; it < NCB; ++it) async_copy16(bSrc[it] + k0, &Bs[bOff[it]]);
        __syncthreads();

#pragma unroll
        for (int k2 = 0; k2 < 2; ++k2) {
            bf16x8 af[4], bfr[NT];
#pragma unroll
            for (int mt = 0; mt < 4; ++mt) {
                int m = wm * 64 + mt * 16 + l16;
                int blk = (k2 * 4 + q) ^ (m & 7);
                af[mt] = *(const bf16x8*)&As[m * BK + blk * 8];
            }
#pragma unroll
            for (int nt = 0; nt < NT; ++nt) {
                int nn = wn * (BN / 2) + nt * 16 + l16;
                int blk = (k2 * 4 + q) ^ (nn & 7);
                bfr[nt] = *(const bf16x8*)&Bs[nn * BK + blk * 8];
            }
#pragma unroll
            for (int mt = 0; mt < 4; ++mt)
#pragma unroll
                for (int nt = 0; nt < NT; ++nt)
                    acc[mt][nt] = __builtin_amdgcn_mfma_f32_16x16x32_bf16(
                        af[mt], bfr[nt], acc[mt][nt], 0, 0, 0);
        }
        __syncthreads();
    }

    // Epilogue. C/D layout: col = lane&15, row = (lane>>4)*4 + reg
    const int row0 = bm * BM + wm * 64;
    const int col0 = bn * BN + wn * (BN / 2);
#pragma unroll
    for (int mt = 0; mt < 4; ++mt) {
#pragma unroll
        for (int nt = 0; nt < NT; ++nt) {
#pragma unroll
            for (int r = 0; r < 4; ++r) {
                int grow = row0 + mt * 16 + q * 4 + r;
                int gcol = col0 + nt * 16 + l16;
                float v = acc[mt][nt][r] * alpha;
                if (ATOMIC)
                    atomicAdd((float*)Cp + (size_t)grow * ldc + gcol, v);
                else if (OUTBF16)
                    ((bf16_t*)Cp)[(size_t)grow * ldc + gcol] = (bf16_t)v;
                else
                    ((float*)Cp)[(size_t)grow * ldc + gcol] = v;
            }
        }
    }
}

// Fused projections: blocks 0..511 -> QK = x @ [Wq;Wk]^T  [4096,2048]
//                    blocks 512..767 -> Vt = Wv @ x^T      [1024,4096]
// Both K=1024 (nk=16), uniform work -> 768 balanced blocks (3/CU).
__global__ __launch_bounds__(256) void k_qkv(const bf16_t* __restrict__ xb,
                                             const bf16_t* __restrict__ wqk,
                                             const bf16_t* __restrict__ wvb,
                                             bf16_t* __restrict__ qk,
                                             bf16_t* __restrict__ vt) {
    __shared__ __attribute__((aligned(16))) bf16_t As[128 * 64];
    __shared__ __attribute__((aligned(16))) bf16_t Bs[128 * 64];
    int b = blockIdx.x;
    if (b < 512) {
        int bm = b >> 4, bn = b & 15;
        gemm_tile<128, true, false>(xb, 1024, wqk, 1024, qk, 2048, bm, bn, 0, 16, 1.f, As, Bs);
    } else {
        int t = b - 512;
        int bm = t >> 5, bn = t & 31;
        gemm_tile<128, true, false>(wvb, 1024, xb, 1024, vt, 4096, bm, bn, 0, 16, 1.f, As, Bs);
    }
}

// S = (Q @ K^T)/32, lower-triangular 128x64 tiles only: 1056 live blocks.
__global__ __launch_bounds__(256) void k_scores(const bf16_t* __restrict__ qk,
                                                bf16_t* __restrict__ S) {
    __shared__ __attribute__((aligned(16))) bf16_t As[128 * 64];
    __shared__ __attribute__((aligned(16))) bf16_t Bs[64 * 64];
    int bn = blockIdx.x, bm = blockIdx.y;
    if (bn > 2 * bm + 1) return;  // tile fully above diagonal
    gemm_tile<64, true, false>(qk, 2048, qk + 1024, 2048, S, 4096, bm, bn, 0, 16, 0.03125f,
                               As, Bs);
}

// O = P @ V, split-K in chunks of 1024 (16 kb-iters max): per row-block bm,
// 8 bn-tiles x ceil((bm+1)/8) splits -> 640 balanced blocks, f32 atomics.
__global__ __launch_bounds__(256) void k_pv(const bf16_t* __restrict__ S,
                                            const bf16_t* __restrict__ vt,
                                            float* __restrict__ out) {
    __shared__ __attribute__((aligned(16))) bf16_t As[128 * 64];
    __shared__ __attribute__((aligned(16))) bf16_t Bs[128 * 64];
    int b = blockIdx.x;
    int bm = 0, base = 0;
    for (;; ++bm) {
        int c = 8 * ((bm + 8) >> 3);  // 8 * ceil((bm+1)/8)
        if (b < base + c) break;
        base += c;
    }
    int rem = b - base;
    int s = rem >> 3, bn = rem & 7;
    int kb1 = min((s + 1) * 16, 2 * (bm + 1));
    gemm_tile<128, false, true>(S, 4096, vt, 4096, out, 1024, bm, bn, s * 16, kb1, 1.f, As, Bs);
}

// Causal softmax per row, in place; zero-fills [L, Lpad) so PV can read
// whole 128-wide K-blocks. Vectorized bf16x8, single exp pass (cached in LDS).
__global__ __launch_bounds__(256) void softmax_causal(bf16_t* __restrict__ S, int n) {
    const int i = blockIdx.x;
    const int L = i + 1;
    const int Lpad = min(n, ((i >> 7) + 1) << 7);
    __shared__ float buf[4096];
    __shared__ float red[8];
    bf16_t* row = S + (size_t)i * n;

    for (int j0 = threadIdx.x * 8; j0 < Lpad; j0 += 2048) {
        bf16x8 v = *(const bf16x8*)(row + j0);
#pragma unroll
        for (int u = 0; u < 8; ++u) buf[j0 + u] = (j0 + u < L) ? (float)v[u] : -3.0e38f;
    }
    __syncthreads();

    float m = -3.4e38f;
    for (int j = threadIdx.x; j < Lpad; j += 256) m = fmaxf(m, buf[j]);
#pragma unroll
    for (int off = 32; off; off >>= 1) m = fmaxf(m, __shfl_xor(m, off, 64));
    if ((threadIdx.x & 63) == 0) red[threadIdx.x >> 6] = m;
    __syncthreads();
    m = fmaxf(fmaxf(red[0], red[1]), fmaxf(red[2], red[3]));

    float s = 0.f;
    for (int j = threadIdx.x; j < Lpad; j += 256) {
        float e = __expf(buf[j] - m);  // exp(-3e38 - m) == 0 for the pad region
        buf[j] = e;
        s += e;
    }
#pragma unroll
    for (int off = 32; off; off >>= 1) s += __shfl_xor(s, off, 64);
    if ((threadIdx.x & 63) == 0) red[4 + (threadIdx.x >> 6)] = s;
    __syncthreads();
    s = (red[4] + red[5]) + (red[6] + red[7]);
    float inv = 1.f / s;

    for (int j0 = threadIdx.x * 8; j0 < Lpad; j0 += 2048) {
        bf16x8 o;
#pragma unroll
        for (int u = 0; u < 8; ++u) o[u] = (bf16_t)(buf[j0 + u] * inv);
        *(bf16x8*)(row + j0) = o;
    }
}

// fp32 -> bf16 casts: x -> x_bf, Wq|Wk -> Wqk (concat), Wv -> Wv_bf.
__global__ __launch_bounds__(256) void cast_to_bf16(const float* __restrict__ x,
                                                    const float* __restrict__ Wq,
                                                    const float* __restrict__ Wk,
                                                    const float* __restrict__ Wv,
                                                    bf16_t* __restrict__ xb,
                                                    bf16_t* __restrict__ wqk,
                                                    bf16_t* __restrict__ wv) {
    const int NX = (4096 * 1024) / 4;
    const int NW = (1024 * 1024) / 4;
    int idx = blockIdx.x * 256 + threadIdx.x;
    const float* src;
    bf16_t* dst;
    int off;
    if (idx < NX) {
        src = x; dst = xb; off = idx;
    } else if (idx < NX + NW) {
        src = Wq; dst = wqk; off = idx - NX;
    } else if (idx < NX + 2 * NW) {
        src = Wk; dst = wqk + (size_t)NW * 4; off = idx - NX - NW;
    } else {
        src = Wv; dst = wv; off = idx - NX - 2 * NW;
    }
    float4 f = ((const float4*)src)[off];
    bf16x4 o;
    o.x = (bf16_t)f.x; o.y = (bf16_t)f.y; o.z = (bf16_t)f.z; o.w = (bf16_t)f.w;
    *(bf16x4*)(dst + (size_t)off * 4) = o;
}

extern "C" void kernel_launch(void* const* d_in, const int* in_sizes, int n_in,
                              void* d_out, int out_size, void* d_ws, size_t ws_size,
                              hipStream_t stream) {
    (void)in_sizes; (void)n_in; (void)out_size; (void)ws_size;
    const float* x  = (const float*)d_in[0];
    const float* Wq = (const float*)d_in[1];
    const float* Wk = (const float*)d_in[2];
    const float* Wv = (const float*)d_in[3];
    float* out = (float*)d_out;

    char* ws = (char*)d_ws;
    bf16_t* xb  = (bf16_t*)(ws + (size_t)0);
    bf16_t* wqk = (bf16_t*)(ws + ((size_t)8 << 20));
    bf16_t* wvb = (bf16_t*)(ws + ((size_t)12 << 20));
    bf16_t* qk  = (bf16_t*)(ws + ((size_t)14 << 20));
    bf16_t* vt  = (bf16_t*)(ws + ((size_t)30 << 20));
    bf16_t* S   = (bf16_t*)(ws + ((size_t)38 << 20));

    // out is accumulated by k_pv atomics -> zero it (async memset is capturable)
    hipMemsetAsync(out, 0, (size_t)4096 * 1024 * sizeof(float), stream);

    cast_to_bf16<<<7168, 256, 0, stream>>>(x, Wq, Wk, Wv, xb, wqk, wvb);

    // QK = x@[Wq;Wk]^T and Vt = Wv@x^T, one dispatch (768 blocks, 3/CU)
    k_qkv<<<768, 256, 0, stream>>>(xb, wqk, wvb, qk, vt);

    // S = (Q @ K^T)/32, causal 128x64 tiles (1056 live blocks, 4.1/CU)
    k_scores<<<dim3(64, 32), 256, 0, stream>>>(qk, S);

    softmax_causal<<<4096, 256, 0, stream>>>(S, 4096);

    // out += P @ V, split-K (640 balanced blocks, 2.5/CU)
    k_pv<<<640, 256, 0, stream>>>(S, vt, out);
}

// Round 3
// 219.815 us; speedup vs baseline: 1.1622x; 1.0172x over previous
//
#include <hip/hip_runtime.h>
#include <hip/hip_bf16.h>

// Causal attention, S=4096, d=1024, fp32 in/out, bf16 MFMA internally.
// Reference's full-row softmax -> tril -> renormalize == causal softmax
// (row max & Z cancel), so only the lower triangle is computed.
//
// Round-3 structure:
//  - k_pv: split-K (chunks of <=20 kb-iters); single-split tiles store direct,
//    multi-split tiles write fp32 partials into dead ws [0,30M) -> k_reduce.
//    (round-2 used 10.5M scalar atomicAdds: WRITE_SIZE 41MB vs 16.8 ideal)
//  - all grids ordered so blocks sharing an A-strip are congruent mod 8
//    (XCD-L2 locality heuristic; softmax rows remapped to the writer's XCD)
//
// Workspace layout (70 MB):
//   [0,30M)   dead zone reused for PV partials (x_bf/Wqk/Wv_bf/QK live earlier)
//   [0,8M)    x_bf  [4096,1024] bf16
//   [8M,12M)  Wqk   [2048,1024] bf16   (Wq rows 0..1023, Wk rows 1024..2047)
//   [12M,14M) Wv_bf [1024,1024] bf16
//   [14M,30M) QK    [4096,2048] bf16   (Q cols 0..1023, K cols 1024..2047)
//   [30M,38M) Vt    [1024,4096] bf16   (V^T, computed directly as Wv @ x^T)
//   [38M,70M) S/P   [4096,4096] bf16   (scores -> probs in place)

typedef __bf16 bf16_t;
typedef __bf16 bf16x4 __attribute__((ext_vector_type(4)));
typedef __bf16 bf16x8 __attribute__((ext_vector_type(8)));
typedef float f32x4 __attribute__((ext_vector_type(4)));

#define AS1 __attribute__((address_space(1)))
#define AS3 __attribute__((address_space(3)))

__device__ __forceinline__ void async_copy16(const void* g, void* l) {
    // 16B/lane direct global->LDS; LDS dest = wave-uniform base + lane*16
    __builtin_amdgcn_global_load_lds((AS1 void*)(g), (AS3 void*)(l), 16, 0, 0);
}

// One 128xBN tile of C = alpha * A.B^T (A,B K-contiguous, pre-offset to the
// tile's first row). BK=64, XOR-swizzled LDS (chunk b of row r holds k-block
// b^(r&7)) -> conflict-free staging writes and ds_read_b128 fragment reads.
// kb in [kb0,kb1) for split-K. C pre-offset to tile origin, leading dim ldc.
template <int BN, typename OutT>
__device__ __forceinline__ void gemm_tile(const bf16_t* __restrict__ A, int lda,
                                          const bf16_t* __restrict__ B, int ldb,
                                          OutT* __restrict__ C, int ldc,
                                          int kb0, int kb1, float alpha,
                                          bf16_t* __restrict__ As, bf16_t* __restrict__ Bs) {
    constexpr int BK = 64;
    constexpr int NT = BN / 32;   // 16-col MFMA tiles per wave (wave = 64 x BN/2)
    constexpr int NCB = BN / 32;  // B staging chunks per thread

    const int tid = threadIdx.x;
    const int lane = tid & 63, wave = tid >> 6;
    const int wm = wave >> 1, wn = wave & 1;
    const int q = lane >> 4, l16 = lane & 15;

    f32x4 acc[4][NT] = {};

    const bf16_t* aSrc[4];
    int aOff[4];
#pragma unroll
    for (int it = 0; it < 4; ++it) {
        int c = it * 256 + tid;
        int r = c >> 3, b = c & 7;
        int sb = b ^ (r & 7);
        aSrc[it] = A + (size_t)r * lda + sb * 8;
        aOff[it] = c * 8;
    }
    const bf16_t* bSrc[NCB];
    int bOff[NCB];
#pragma unroll
    for (int it = 0; it < NCB; ++it) {
        int c = it * 256 + tid;
        int r = c >> 3, b = c & 7;
        int sb = b ^ (r & 7);
        bSrc[it] = B + (size_t)r * ldb + sb * 8;
        bOff[it] = c * 8;
    }

    for (int kb = kb0; kb < kb1; ++kb) {
        const int k0 = kb * BK;
#pragma unroll
        for (int it = 0; it < 4; ++it) async_copy16(aSrc[it] + k0, &As[aOff[it]]);
#pragma unroll
        for (int it = 0; it < NCB; ++it) async_copy16(bSrc[it] + k0, &Bs[bOff[it]]);
        __syncthreads();

#pragma unroll
        for (int k2 = 0; k2 < 2; ++k2) {
            bf16x8 af[4], bfr[NT];
#pragma unroll
            for (int mt = 0; mt < 4; ++mt) {
                int m = wm * 64 + mt * 16 + l16;
                int blk = (k2 * 4 + q) ^ (m & 7);
                af[mt] = *(const bf16x8*)&As[m * BK + blk * 8];
            }
#pragma unroll
            for (int nt = 0; nt < NT; ++nt) {
                int nn = wn * (BN / 2) + nt * 16 + l16;
                int blk = (k2 * 4 + q) ^ (nn & 7);
                bfr[nt] = *(const bf16x8*)&Bs[nn * BK + blk * 8];
            }
#pragma unroll
            for (int mt = 0; mt < 4; ++mt)
#pragma unroll
                for (int nt = 0; nt < NT; ++nt)
                    acc[mt][nt] = __builtin_amdgcn_mfma_f32_16x16x32_bf16(
                        af[mt], bfr[nt], acc[mt][nt], 0, 0, 0);
        }
        __syncthreads();
    }

    // Epilogue. C/D layout: col = lane&15, row = (lane>>4)*4 + reg
    const int row0 = wm * 64;
    const int col0 = wn * (BN / 2);
#pragma unroll
    for (int mt = 0; mt < 4; ++mt) {
#pragma unroll
        for (int nt = 0; nt < NT; ++nt) {
#pragma unroll
            for (int r = 0; r < 4; ++r) {
                int grow = row0 + mt * 16 + q * 4 + r;
                int gcol = col0 + nt * 16 + l16;
                C[(size_t)grow * ldc + gcol] = (OutT)(acc[mt][nt][r] * alpha);
            }
        }
    }
}

// Fused projections, 768 blocks (3/CU):
//   b in [0,512):   QK = x @ [Wq;Wk]^T  [4096,2048]; bm fastest -> XCD=bm%8
//   b in [512,768): Vt = Wv @ x^T       [1024,4096]; bmv fastest -> XCD=bmv%8
__global__ __launch_bounds__(256) void k_qkv(const bf16_t* __restrict__ xb,
                                             const bf16_t* __restrict__ wqk,
                                             const bf16_t* __restrict__ wvb,
                                             bf16_t* __restrict__ qk,
                                             bf16_t* __restrict__ vt) {
    __shared__ __attribute__((aligned(16))) bf16_t As[128 * 64];
    __shared__ __attribute__((aligned(16))) bf16_t Bs[128 * 64];
    int b = blockIdx.x;
    const bf16_t *A, *B;
    bf16_t* C;
    int ldc;
    if (b < 512) {
        int bm = b & 31, bn = b >> 5;  // bn 0..15
        A = xb + (size_t)bm * 128 * 1024;
        B = wqk + (size_t)bn * 128 * 1024;
        C = qk + (size_t)bm * 128 * 2048 + bn * 128;
        ldc = 2048;
    } else {
        int t = b - 512;
        int bm = t & 7, bn = t >> 3;  // bn 0..31
        A = wvb + (size_t)bm * 128 * 1024;
        B = xb + (size_t)bn * 128 * 1024;
        C = vt + (size_t)bm * 128 * 4096 + bn * 128;
        ldc = 4096;
    }
    gemm_tile<128, bf16_t>(A, 1024, B, 1024, C, ldc, 0, 16, 1.f, As, Bs);
}

// S = (Q @ K^T)/32, lower-triangular 128x64 tiles: 1056 live blocks (4.1/CU).
// Grid dim3(32,64): x=bm fastest -> same-bm blocks on XCD bm%8 (A-strip reuse).
__global__ __launch_bounds__(256) void k_scores(const bf16_t* __restrict__ qk,
                                                bf16_t* __restrict__ S) {
    __shared__ __attribute__((aligned(16))) bf16_t As[128 * 64];
    __shared__ __attribute__((aligned(16))) bf16_t Bs[64 * 64];
    int bm = blockIdx.x, bn = blockIdx.y;
    if (bn > 2 * bm + 1) return;  // tile fully above diagonal
    gemm_tile<64, bf16_t>(qk + (size_t)bm * 128 * 2048, 2048,
                          qk + 1024 + (size_t)bn * 64 * 2048, 2048,
                          S + (size_t)bm * 128 * 4096 + bn * 64, 4096,
                          0, 16, 0.03125f, As, Bs);
}

// O = P @ V. Split-K in chunks of 20 kb-iters (balanced; max 20 per block).
// Grid 1024 = 128 group slots (g = s*32+bm, so XCD = bm%8) x 8 bn; dead slots
// (s >= nsplit(bm)) exit. Single-split tiles (bm<=9) store straight to out;
// multi-split tiles write fp32 128x128 partials into ws[0,30M) for k_reduce.
__global__ __launch_bounds__(256) void k_pv(const bf16_t* __restrict__ S,
                                            const bf16_t* __restrict__ vt,
                                            float* __restrict__ out,
                                            float* __restrict__ partials) {
    __shared__ __attribute__((aligned(16))) bf16_t As[128 * 64];
    __shared__ __attribute__((aligned(16))) bf16_t Bs[128 * 64];
    int b = blockIdx.x;
    int g = b & 127, bn = b >> 7;
    int bm = g & 31, s = g >> 5;
    int nk = 2 * (bm + 1);
    int ns = (nk + 19) / 20;
    if (s >= ns) return;
    int kb0 = s * 20;
    int kb1 = min(kb0 + 20, nk);

    float* C;
    int ldc;
    if (ns == 1) {
        C = out + (size_t)bm * 128 * 1024 + bn * 128;
        ldc = 1024;
    } else {
        int cum = 0;
        for (int u = 10; u < bm; ++u) cum += (2 * (u + 1) + 19) / 20;
        C = partials + ((size_t)(cum + s) * 8 + bn) * 16384;
        ldc = 128;
    }
    gemm_tile<128, float>(S + (size_t)bm * 128 * 4096, 4096,
                          vt + (size_t)bn * 128 * 4096, 4096,
                          C, ldc, kb0, kb1, 1.f, As, Bs);
}

// out tiles for bm in [10,31]: sum 2..4 fp32 partials. Grid 3072 = 192 slots
// (t = bn*24 + (bm-8): XCD = bm%8; t%24<2 dead) x 16 quarters; float4/thread.
__global__ __launch_bounds__(256) void k_reduce(const float* __restrict__ partials,
                                                float* __restrict__ out) {
    int b = blockIdx.x;
    int t = b % 192, p = b / 192;
    int d = t % 24;
    if (d < 2) return;
    int bm = d + 8, bn = t / 24;
    int ns = (2 * (bm + 1) + 19) / 20;
    int cum = 0;
    for (int u = 10; u < bm; ++u) cum += (2 * (u + 1) + 19) / 20;

    int idx = p * 1024 + threadIdx.x * 4;
    int lr = idx >> 7, lc = idx & 127;
    float sx = 0.f, sy = 0.f, sz = 0.f, sw = 0.f;
    for (int u = 0; u < ns; ++u) {
        const float4 v = *(const float4*)(partials + ((size_t)(cum + u) * 8 + bn) * 16384 + idx);
        sx += v.x; sy += v.y; sz += v.z; sw += v.w;
    }
    float4 o = {sx, sy, sz, sw};
    *(float4*)(out + (size_t)(bm * 128 + lr) * 1024 + bn * 128 + lc) = o;
}

// Causal softmax per row, in place; zero-fills [L, Lpad) so PV reads whole
// 128-wide K-blocks. Rows remapped so row-block bm runs on XCD bm%8 (the XCD
// whose L2 holds the freshly-written scores).
__global__ __launch_bounds__(256) void softmax_causal(bf16_t* __restrict__ S, int n) {
    const int b = blockIdx.x;
    const int i = (b & 31) * 128 + (b >> 5);
    const int L = i + 1;
    const int Lpad = min(n, ((i >> 7) + 1) << 7);
    __shared__ float buf[4096];
    __shared__ float red[8];
    bf16_t* row = S + (size_t)i * n;

    for (int j0 = threadIdx.x * 8; j0 < Lpad; j0 += 2048) {
        bf16x8 v = *(const bf16x8*)(row + j0);
#pragma unroll
        for (int u = 0; u < 8; ++u) buf[j0 + u] = (j0 + u < L) ? (float)v[u] : -3.0e38f;
    }
    __syncthreads();

    float m = -3.4e38f;
    for (int j = threadIdx.x; j < Lpad; j += 256) m = fmaxf(m, buf[j]);
#pragma unroll
    for (int off = 32; off; off >>= 1) m = fmaxf(m, __shfl_xor(m, off, 64));
    if ((threadIdx.x & 63) == 0) red[threadIdx.x >> 6] = m;
    __syncthreads();
    m = fmaxf(fmaxf(red[0], red[1]), fmaxf(red[2], red[3]));

    float s = 0.f;
    for (int j = threadIdx.x; j < Lpad; j += 256) {
        float e = __expf(buf[j] - m);  // exp(-3e38 - m) == 0 for the pad region
        buf[j] = e;
        s += e;
    }
#pragma unroll
    for (int off = 32; off; off >>= 1) s += __shfl_xor(s, off, 64);
    if ((threadIdx.x & 63) == 0) red[4 + (threadIdx.x >> 6)] = s;
    __syncthreads();
    s = (red[4] + red[5]) + (red[6] + red[7]);
    float inv = 1.f / s;

    for (int j0 = threadIdx.x * 8; j0 < Lpad; j0 += 2048) {
        bf16x8 o;
#pragma unroll
        for (int u = 0; u < 8; ++u) o[u] = (bf16_t)(buf[j0 + u] * inv);
        *(bf16x8*)(row + j0) = o;
    }
}

// fp32 -> bf16 casts: x -> x_bf, Wq|Wk -> Wqk (concat), Wv -> Wv_bf.
__global__ __launch_bounds__(256) void cast_to_bf16(const float* __restrict__ x,
                                                    const float* __restrict__ Wq,
                                                    const float* __restrict__ Wk,
                                                    const float* __restrict__ Wv,
                                                    bf16_t* __restrict__ xb,
                                                    bf16_t* __restrict__ wqk,
                                                    bf16_t* __restrict__ wv) {
    const int NX = (4096 * 1024) / 4;
    const int NW = (1024 * 1024) / 4;
    int idx = blockIdx.x * 256 + threadIdx.x;
    const float* src;
    bf16_t* dst;
    int off;
    if (idx < NX) {
        src = x; dst = xb; off = idx;
    } else if (idx < NX + NW) {
        src = Wq; dst = wqk; off = idx - NX;
    } else if (idx < NX + 2 * NW) {
        src = Wk; dst = wqk + (size_t)NW * 4; off = idx - NX - NW;
    } else {
        src = Wv; dst = wv; off = idx - NX - 2 * NW;
    }
    float4 f = ((const float4*)src)[off];
    bf16x4 o;
    o.x = (bf16_t)f.x; o.y = (bf16_t)f.y; o.z = (bf16_t)f.z; o.w = (bf16_t)f.w;
    *(bf16x4*)(dst + (size_t)off * 4) = o;
}

extern "C" void kernel_launch(void* const* d_in, const int* in_sizes, int n_in,
                              void* d_out, int out_size, void* d_ws, size_t ws_size,
                              hipStream_t stream) {
    (void)in_sizes; (void)n_in; (void)out_size; (void)ws_size;
    const float* x  = (const float*)d_in[0];
    const float* Wq = (const float*)d_in[1];
    const float* Wk = (const float*)d_in[2];
    const float* Wv = (const float*)d_in[3];
    float* out = (float*)d_out;

    char* ws = (char*)d_ws;
    bf16_t* xb   = (bf16_t*)(ws + (size_t)0);
    bf16_t* wqk  = (bf16_t*)(ws + ((size_t)8 << 20));
    bf16_t* wvb  = (bf16_t*)(ws + ((size_t)12 << 20));
    bf16_t* qk   = (bf16_t*)(ws + ((size_t)14 << 20));
    bf16_t* vt   = (bf16_t*)(ws + ((size_t)30 << 20));
    bf16_t* S    = (bf16_t*)(ws + ((size_t)38 << 20));
    float* parts = (float*)(ws + (size_t)0);  // reuses [0,30M): dead during PV

    cast_to_bf16<<<7168, 256, 0, stream>>>(x, Wq, Wk, Wv, xb, wqk, wvb);

    // QK = x@[Wq;Wk]^T and Vt = Wv@x^T, one dispatch (768 blocks, 3/CU)
    k_qkv<<<768, 256, 0, stream>>>(xb, wqk, wvb, qk, vt);

    // S = (Q @ K^T)/32, causal 128x64 tiles (1056 live blocks, 4.1/CU)
    k_scores<<<dim3(32, 64), 256, 0, stream>>>(qk, S);

    softmax_causal<<<4096, 256, 0, stream>>>(S, 4096);

    // out = P @ V: balanced split-K, partials for multi-split tiles
    k_pv<<<1024, 256, 0, stream>>>(S, vt, out, parts);
    k_reduce<<<3072, 256, 0, stream>>>(parts, out);
}

// Round 4
// 201.951 us; speedup vs baseline: 1.2650x; 1.0885x over previous
//
#include <hip/hip_runtime.h>
#include <hip/hip_bf16.h>

// Causal attention, S=4096, d=1024, fp32 in/out, bf16 MFMA internally.
// Reference's full-row softmax -> tril -> renormalize == causal softmax
// (row max & Z cancel), so only the lower triangle is computed.
//
// Round-4: fix grid<->CU aliasing. Blocks dispatch round-robin with period
// 256 (8 XCD x 32 CU); any mapping where work depends on (blockIdx mod 256)
// leaves CUs idle or serialized (round-3 k_pv: 47% of CUs got only dead
// slots -> Occupancy 8%, 57us). All grids are now compact (no dead blocks)
// and every 256-consecutive-blockIdx window carries uniform work.
//
// Workspace layout (70 MB):
//   [0,30M)   dead zone reused for PV fp32 partials (58 groups x 8 bn x 64KB)
//   [0,8M)    x_bf  [4096,1024] bf16
//   [8M,12M)  Wqk   [2048,1024] bf16   (Wq rows 0..1023, Wk rows 1024..2047)
//   [12M,14M) Wv_bf [1024,1024] bf16
//   [14M,30M) QK    [4096,2048] bf16   (Q cols 0..1023, K cols 1024..2047)
//   [30M,38M) Vt    [1024,4096] bf16   (V^T, computed directly as Wv @ x^T)
//   [38M,70M) S/P   [4096,4096] bf16   (scores -> probs in place)

typedef __bf16 bf16_t;
typedef __bf16 bf16x4 __attribute__((ext_vector_type(4)));
typedef __bf16 bf16x8 __attribute__((ext_vector_type(8)));
typedef float f32x4 __attribute__((ext_vector_type(4)));

#define AS1 __attribute__((address_space(1)))
#define AS3 __attribute__((address_space(3)))

__device__ __forceinline__ void async_copy16(const void* g, void* l) {
    // 16B/lane direct global->LDS; LDS dest = wave-uniform base + lane*16
    __builtin_amdgcn_global_load_lds((AS1 void*)(g), (AS3 void*)(l), 16, 0, 0);
}

// One 128xBN tile of C = alpha * A.B^T (A,B K-contiguous, pre-offset to the
// tile's first row). BK=64, XOR-swizzled LDS (chunk b of row r holds k-block
// b^(r&7)) -> conflict-free staging writes and ds_read_b128 fragment reads.
// kb in [kb0,kb1) for split-K. C pre-offset to tile origin, leading dim ldc.
template <int BN, typename OutT>
__device__ __forceinline__ void gemm_tile(const bf16_t* __restrict__ A, int lda,
                                          const bf16_t* __restrict__ B, int ldb,
                                          OutT* __restrict__ C, int ldc,
                                          int kb0, int kb1, float alpha,
                                          bf16_t* __restrict__ As, bf16_t* __restrict__ Bs) {
    constexpr int BK = 64;
    constexpr int NT = BN / 32;   // 16-col MFMA tiles per wave (wave = 64 x BN/2)
    constexpr int NCB = BN / 32;  // B staging chunks per thread

    const int tid = threadIdx.x;
    const int lane = tid & 63, wave = tid >> 6;
    const int wm = wave >> 1, wn = wave & 1;
    const int q = lane >> 4, l16 = lane & 15;

    f32x4 acc[4][NT] = {};

    const bf16_t* aSrc[4];
    int aOff[4];
#pragma unroll
    for (int it = 0; it < 4; ++it) {
        int c = it * 256 + tid;
        int r = c >> 3, b = c & 7;
        int sb = b ^ (r & 7);
        aSrc[it] = A + (size_t)r * lda + sb * 8;
        aOff[it] = c * 8;
    }
    const bf16_t* bSrc[NCB];
    int bOff[NCB];
#pragma unroll
    for (int it = 0; it < NCB; ++it) {
        int c = it * 256 + tid;
        int r = c >> 3, b = c & 7;
        int sb = b ^ (r & 7);
        bSrc[it] = B + (size_t)r * ldb + sb * 8;
        bOff[it] = c * 8;
    }

    for (int kb = kb0; kb < kb1; ++kb) {
        const int k0 = kb * BK;
#pragma unroll
        for (int it = 0; it < 4; ++it) async_copy16(aSrc[it] + k0, &As[aOff[it]]);
#pragma unroll
        for (int it = 0; it < NCB; ++it) async_copy16(bSrc[it] + k0, &Bs[bOff[it]]);
        __syncthreads();

#pragma unroll
        for (int k2 = 0; k2 < 2; ++k2) {
            bf16x8 af[4], bfr[NT];
#pragma unroll
            for (int mt = 0; mt < 4; ++mt) {
                int m = wm * 64 + mt * 16 + l16;
                int blk = (k2 * 4 + q) ^ (m & 7);
                af[mt] = *(const bf16x8*)&As[m * BK + blk * 8];
            }
#pragma unroll
            for (int nt = 0; nt < NT; ++nt) {
                int nn = wn * (BN / 2) + nt * 16 + l16;
                int blk = (k2 * 4 + q) ^ (nn & 7);
                bfr[nt] = *(const bf16x8*)&Bs[nn * BK + blk * 8];
            }
#pragma unroll
            for (int mt = 0; mt < 4; ++mt)
#pragma unroll
                for (int nt = 0; nt < NT; ++nt)
                    acc[mt][nt] = __builtin_amdgcn_mfma_f32_16x16x32_bf16(
                        af[mt], bfr[nt], acc[mt][nt], 0, 0, 0);
        }
        __syncthreads();
    }

    // Epilogue. C/D layout: col = lane&15, row = (lane>>4)*4 + reg
    const int row0 = wm * 64;
    const int col0 = wn * (BN / 2);
#pragma unroll
    for (int mt = 0; mt < 4; ++mt) {
#pragma unroll
        for (int nt = 0; nt < NT; ++nt) {
#pragma unroll
            for (int r = 0; r < 4; ++r) {
                int grow = row0 + mt * 16 + q * 4 + r;
                int gcol = col0 + nt * 16 + l16;
                C[(size_t)grow * ldc + gcol] = (OutT)(acc[mt][nt][r] * alpha);
            }
        }
    }
}

// Fused projections, 768 blocks (3/CU), every block exactly 16 kb-iters:
//   b in [0,512):   QK = x @ [Wq;Wk]^T  [4096,2048]
//   b in [512,768): Vt = Wv @ x^T       [1024,4096]
__global__ __launch_bounds__(256) void k_qkv(const bf16_t* __restrict__ xb,
                                             const bf16_t* __restrict__ wqk,
                                             const bf16_t* __restrict__ wvb,
                                             bf16_t* __restrict__ qk,
                                             bf16_t* __restrict__ vt) {
    __shared__ __attribute__((aligned(16))) bf16_t As[128 * 64];
    __shared__ __attribute__((aligned(16))) bf16_t Bs[128 * 64];
    int b = blockIdx.x;
    const bf16_t *A, *B;
    bf16_t* C;
    int ldc;
    if (b < 512) {
        int bm = b & 31, bn = b >> 5;  // bn 0..15
        A = xb + (size_t)bm * 128 * 1024;
        B = wqk + (size_t)bn * 128 * 1024;
        C = qk + (size_t)bm * 128 * 2048 + bn * 128;
        ldc = 2048;
    } else {
        int t = b - 512;
        int bm = t & 7, bn = t >> 3;  // bn 0..31
        A = wvb + (size_t)bm * 128 * 1024;
        B = xb + (size_t)bn * 128 * 1024;
        C = vt + (size_t)bm * 128 * 4096 + bn * 128;
        ldc = 4096;
    }
    gemm_tile<128, bf16_t>(A, 1024, B, 1024, C, ldc, 0, 16, 1.f, As, Bs);
}

// S = (Q @ K^T)/32, lower-triangular 128x64 tiles. Compact 1-D grid of all
// 1056 live tiles: t = bm^2 + bm + bn, bn in [0, 2bm+2). Every block is
// exactly 16 kb-iters -> per-CU load is uniform for any dispatch scheme.
__global__ __launch_bounds__(256) void k_scores(const bf16_t* __restrict__ qk,
                                                bf16_t* __restrict__ S) {
    __shared__ __attribute__((aligned(16))) bf16_t As[128 * 64];
    __shared__ __attribute__((aligned(16))) bf16_t Bs[64 * 64];
    int t = blockIdx.x;
    int bm = (int)((sqrtf(4.f * (float)t + 1.f) - 1.f) * 0.5f);
    while (bm * bm + bm > t) --bm;
    while ((bm + 1) * (bm + 1) + (bm + 1) <= t) ++bm;
    int bn = t - bm * bm - bm;  // 0 .. 2bm+1
    gemm_tile<64, bf16_t>(qk + (size_t)bm * 128 * 2048, 2048,
                          qk + 1024 + (size_t)bn * 64 * 2048, 2048,
                          S + (size_t)bm * 128 * 4096 + bn * 64, 4096,
                          0, 16, 0.03125f, As, Bs);
}

// O = P @ V, split-K. 544 compact blocks: bn = b&7 (8 col tiles), g = b>>3
// walks 68 (bm, s) groups; split lengths equalized (kb = s*nk/ns). Single-
// split tiles (bm<=9) store straight to out; multi-split tiles write fp32
// 128x128 partials into ws[0,30M) for k_reduce.
__global__ __launch_bounds__(256) void k_pv(const bf16_t* __restrict__ S,
                                            const bf16_t* __restrict__ vt,
                                            float* __restrict__ out,
                                            float* __restrict__ partials) {
    __shared__ __attribute__((aligned(16))) bf16_t As[128 * 64];
    __shared__ __attribute__((aligned(16))) bf16_t Bs[128 * 64];
    int b = blockIdx.x;
    int bn = b & 7, g = b >> 3;
    int bm, s;
    if (g < 10)      { bm = g;                s = 0; }
    else if (g < 30) { bm = 10 + (g - 10) / 2; s = (g - 10) % 2; }
    else if (g < 60) { bm = 20 + (g - 30) / 3; s = (g - 30) % 3; }
    else             { bm = 30 + (g - 60) / 4; s = (g - 60) % 4; }
    int nk = 2 * (bm + 1);
    int ns = (nk + 19) / 20;
    int kb0 = s * nk / ns;
    int kb1 = (s + 1) * nk / ns;

    float* C;
    int ldc;
    if (ns == 1) {
        C = out + (size_t)bm * 128 * 1024 + bn * 128;
        ldc = 1024;
    } else {
        int cum = (bm < 20) ? (bm - 10) * 2 : (bm < 30) ? 20 + (bm - 20) * 3
                                                        : 50 + (bm - 30) * 4;
        C = partials + ((size_t)(cum + s) * 8 + bn) * 16384;
        ldc = 128;
    }
    gemm_tile<128, float>(S + (size_t)bm * 128 * 4096, 4096,
                          vt + (size_t)bn * 128 * 4096, 4096,
                          C, ldc, kb0, kb1, 1.f, As, Bs);
}

// out tiles for bm in [10,31]: sum 2..4 fp32 partials. Compact 2816 blocks:
// t = b%176 -> (bm-10, bn); p = b/176 -> 1/16th of the 128x128 tile.
__global__ __launch_bounds__(256) void k_reduce(const float* __restrict__ partials,
                                                float* __restrict__ out) {
    int b = blockIdx.x;
    int t = b % 176, p = b / 176;
    int bm = t % 22 + 10, bn = t / 22;
    int ns = (2 * (bm + 1) + 19) / 20;
    int cum = (bm < 20) ? (bm - 10) * 2 : (bm < 30) ? 20 + (bm - 20) * 3
                                                    : 50 + (bm - 30) * 4;
    int idx = p * 1024 + threadIdx.x * 4;
    int lr = idx >> 7, lc = idx & 127;
    float sx = 0.f, sy = 0.f, sz = 0.f, sw = 0.f;
    for (int u = 0; u < ns; ++u) {
        const float4 v = *(const float4*)(partials + ((size_t)(cum + u) * 8 + bn) * 16384 + idx);
        sx += v.x; sy += v.y; sz += v.z; sw += v.w;
    }
    float4 o = {sx, sy, sz, sw};
    *(float4*)(out + (size_t)(bm * 128 + lr) * 1024 + bn * 128 + lc) = o;
}

// Causal softmax per row, in place; zero-fills [L, Lpad) so PV reads whole
// 128-wide K-blocks. Row map i = (b&255)*16 + (b>>8): any 256 consecutive
// blocks span the whole triangle -> per-CU work balanced.
__global__ __launch_bounds__(256) void softmax_causal(bf16_t* __restrict__ S, int n) {
    const int b = blockIdx.x;
    const int i = (b & 255) * 16 + (b >> 8);
    const int L = i + 1;
    const int Lpad = min(n, ((i >> 7) + 1) << 7);
    __shared__ float buf[4096];
    __shared__ float red[8];
    bf16_t* row = S + (size_t)i * n;

    for (int j0 = threadIdx.x * 8; j0 < Lpad; j0 += 2048) {
        bf16x8 v = *(const bf16x8*)(row + j0);
#pragma unroll
        for (int u = 0; u < 8; ++u) buf[j0 + u] = (j0 + u < L) ? (float)v[u] : -3.0e38f;
    }
    __syncthreads();

    float m = -3.4e38f;
    for (int j = threadIdx.x; j < Lpad; j += 256) m = fmaxf(m, buf[j]);
#pragma unroll
    for (int off = 32; off; off >>= 1) m = fmaxf(m, __shfl_xor(m, off, 64));
    if ((threadIdx.x & 63) == 0) red[threadIdx.x >> 6] = m;
    __syncthreads();
    m = fmaxf(fmaxf(red[0], red[1]), fmaxf(red[2], red[3]));

    float s = 0.f;
    for (int j = threadIdx.x; j < Lpad; j += 256) {
        float e = __expf(buf[j] - m);  // exp(-3e38 - m) == 0 for the pad region
        buf[j] = e;
        s += e;
    }
#pragma unroll
    for (int off = 32; off; off >>= 1) s += __shfl_xor(s, off, 64);
    if ((threadIdx.x & 63) == 0) red[4 + (threadIdx.x >> 6)] = s;
    __syncthreads();
    s = (red[4] + red[5]) + (red[6] + red[7]);
    float inv = 1.f / s;

    for (int j0 = threadIdx.x * 8; j0 < Lpad; j0 += 2048) {
        bf16x8 o;
#pragma unroll
        for (int u = 0; u < 8; ++u) o[u] = (bf16_t)(buf[j0 + u] * inv);
        *(bf16x8*)(row + j0) = o;
    }
}

// fp32 -> bf16 casts: x -> x_bf, Wq|Wk -> Wqk (concat), Wv -> Wv_bf.
__global__ __launch_bounds__(256) void cast_to_bf16(const float* __restrict__ x,
                                                    const float* __restrict__ Wq,
                                                    const float* __restrict__ Wk,
                                                    const float* __restrict__ Wv,
                                                    bf16_t* __restrict__ xb,
                                                    bf16_t* __restrict__ wqk,
                                                    bf16_t* __restrict__ wv) {
    const int NX = (4096 * 1024) / 4;
    const int NW = (1024 * 1024) / 4;
    int idx = blockIdx.x * 256 + threadIdx.x;
    const float* src;
    bf16_t* dst;
    int off;
    if (idx < NX) {
        src = x; dst = xb; off = idx;
    } else if (idx < NX + NW) {
        src = Wq; dst = wqk; off = idx - NX;
    } else if (idx < NX + 2 * NW) {
        src = Wk; dst = wqk + (size_t)NW * 4; off = idx - NX - NW;
    } else {
        src = Wv; dst = wv; off = idx - NX - 2 * NW;
    }
    float4 f = ((const float4*)src)[off];
    bf16x4 o;
    o.x = (bf16_t)f.x; o.y = (bf16_t)f.y; o.z = (bf16_t)f.z; o.w = (bf16_t)f.w;
    *(bf16x4*)(dst + (size_t)off * 4) = o;
}

extern "C" void kernel_launch(void* const* d_in, const int* in_sizes, int n_in,
                              void* d_out, int out_size, void* d_ws, size_t ws_size,
                              hipStream_t stream) {
    (void)in_sizes; (void)n_in; (void)out_size; (void)ws_size;
    const float* x  = (const float*)d_in[0];
    const float* Wq = (const float*)d_in[1];
    const float* Wk = (const float*)d_in[2];
    const float* Wv = (const float*)d_in[3];
    float* out = (float*)d_out;

    char* ws = (char*)d_ws;
    bf16_t* xb   = (bf16_t*)(ws + (size_t)0);
    bf16_t* wqk  = (bf16_t*)(ws + ((size_t)8 << 20));
    bf16_t* wvb  = (bf16_t*)(ws + ((size_t)12 << 20));
    bf16_t* qk   = (bf16_t*)(ws + ((size_t)14 << 20));
    bf16_t* vt   = (bf16_t*)(ws + ((size_t)30 << 20));
    bf16_t* S    = (bf16_t*)(ws + ((size_t)38 << 20));
    float* parts = (float*)(ws + (size_t)0);  // reuses [0,30M): dead during PV

    cast_to_bf16<<<7168, 256, 0, stream>>>(x, Wq, Wk, Wv, xb, wqk, wvb);

    // QK = x@[Wq;Wk]^T and Vt = Wv@x^T, one dispatch (768 blocks, 3/CU)
    k_qkv<<<768, 256, 0, stream>>>(xb, wqk, wvb, qk, vt);

    // S = (Q @ K^T)/32, compact causal 128x64 tiles (1056 blocks, 4.1/CU)
    k_scores<<<1056, 256, 0, stream>>>(qk, S);

    softmax_causal<<<4096, 256, 0, stream>>>(S, 4096);

    // out = P @ V: compact balanced split-K + partial reduction
    k_pv<<<544, 256, 0, stream>>>(S, vt, out, parts);
    k_reduce<<<2816, 256, 0, stream>>>(parts, out);
}